// Round 16
// baseline (124.662 us; speedup 1.0000x reference)
//
#include <hip/hip_runtime.h>
#include <hip/hip_bf16.h>

constexpr int LS = 1024;   // sequence length
constexpr int DM = 768;    // model dim
constexpr int NH = 12;     // heads
constexpr int HD = 64;     // head dim
constexpr float EPSF = 1e-5f;
constexpr float ALPHAF = 0.01f;

constexpr int SG = 16;             // state granularity (rows per tile)
constexpr int NTL = LS / SG;       // 64 tiles per head
constexpr int WSZ = DM * DM;       // 589824 elements per weight matrix

typedef unsigned short u16;
typedef __attribute__((ext_vector_type(8))) short bf16x8;
typedef __attribute__((ext_vector_type(8))) unsigned short u16x8;
typedef __attribute__((ext_vector_type(4))) float f32x4;

__device__ __forceinline__ u16 f2b(float f) {
  unsigned u = __float_as_uint(f);
  u += 0x7FFFu + ((u >> 16) & 1u);   // round-to-nearest-even
  return (u16)(u >> 16);
}

// async global->LDS, 16B per lane; LDS dest is wave-uniform base + lane*16
__device__ __forceinline__ void gld16(const void* g, void* l) {
  __builtin_amdgcn_global_load_lds(
      (const __attribute__((address_space(1))) void*)g,
      (__attribute__((address_space(3))) void*)l, 16, 0, 0);
}

// ---------------------------------------------------------------------------
// K0: PREP. grid 192+64+576 = 832 blocks, block 256.
//  b<192 : xtcT[c][h][s] = bf16(x[s][h*64+c])   (B-operand, k-contiguous)
//  b<256 : Afrag[c][d16] = pre-swizzled Toeplitz A-fragments (1KB each)
//          Afrag elem (c*64+d16)*512 + (i*4+g)*8 + kk = bf16(f[16*d16+i-8g-kk][c]), 0 if d<0
//  else  : wT[z][n][k] = bf16(w[k][n])
__global__ __launch_bounds__(256) void prep_kernel(
    const float* __restrict__ x, const float* __restrict__ f,
    const float* __restrict__ wq, const float* __restrict__ wk,
    const float* __restrict__ wv, const float* __restrict__ wo,
    u16* __restrict__ wT, u16* __restrict__ xtcT, u16* __restrict__ Afrag) {
  __shared__ float T[64][65];
  const int b = blockIdx.x;
  const int tid = threadIdx.x;

  if (b < 192) {
    const int h = b / 16, l0 = (b % 16) * 64;
    const int r = tid >> 2, c4 = (tid & 3) * 16;
#pragma unroll
    for (int rep = 0; rep < 4; ++rep) {
      const int cc = c4 + rep * 4;
      const float4 v4 = *(const float4*)(x + (size_t)(l0 + r) * DM + h * HD + cc);
      T[r][cc] = v4.x; T[r][cc + 1] = v4.y; T[r][cc + 2] = v4.z; T[r][cc + 3] = v4.w;
    }
    __syncthreads();
    const int cc = tid & 63, qq = tid >> 6;
    u16* dst = xtcT + ((size_t)cc * 16 + h) * 1024 + l0 + qq * 16;
    u16x8 o0, o1;
#pragma unroll
    for (int e = 0; e < 8; ++e) {
      o0[e] = f2b(T[qq * 16 + e][cc]);
      o1[e] = f2b(T[qq * 16 + 8 + e][cc]);
    }
    *(u16x8*)dst = o0;
    *(u16x8*)(dst + 8) = o1;
    return;
  }
  if (b < 256) {
    const int d16 = b - 192;
    const int c = tid & 63, g = tid >> 6;
    u16* dst = Afrag + ((size_t)c * 64 + d16) * 512 + g * 8;
#pragma unroll
    for (int i = 0; i < 16; ++i) {
      u16x8 o;
#pragma unroll
      for (int kk = 0; kk < 8; ++kk) {
        const int d = 16 * d16 + i - 8 * g - kk;
        const int dc = d < 0 ? 0 : d;
        o[kk] = (d >= 0) ? f2b(f[(size_t)dc * HD + c]) : (u16)0;
      }
      *(u16x8*)(dst + i * 32) = o;   // (i*4+g)*8 = i*32 + g*8
    }
    return;
  }

  // ---- txw ----
  const int b2 = b - 256;
  const int kb = (b2 % 12) * 64, nb = ((b2 / 12) % 12) * 64, z = b2 / 144;
  const float* src = (z == 0) ? wq : (z == 1) ? wk : (z == 2) ? wv : wo;
  u16* dst = wT + (size_t)z * WSZ;
#pragma unroll
  for (int rep = 0; rep < 4; ++rep) {
    const int r = rep * 16 + (tid >> 4);
    const int c4 = (tid & 15) * 4;
    const float4 v4 = *(const float4*)(src + (size_t)(kb + r) * DM + nb + c4);
    T[r][c4] = v4.x; T[r][c4 + 1] = v4.y; T[r][c4 + 2] = v4.z; T[r][c4 + 3] = v4.w;
  }
  __syncthreads();
#pragma unroll
  for (int rep = 0; rep < 4; ++rep) {
    const int n = rep * 16 + (tid >> 4);
    const int k4 = (tid & 15) * 4;
    ushort4 o;
    o.x = f2b(T[k4 + 0][n]); o.y = f2b(T[k4 + 1][n]);
    o.z = f2b(T[k4 + 2][n]); o.w = f2b(T[k4 + 3][n]);
    *(ushort4*)(dst + (size_t)(nb + n) * DM + kb + k4) = o;
  }
}

// ---------------------------------------------------------------------------
// K1: causal conv via MFMA on Toeplitz fragments. grid 256, block 256
// (4 waves; wave = one (channel, group-of-4 l-tiles) job). No LDS, no barriers.
// xt_tile(lt)[i][head] = sum_ks A(d16=lt-2ks) @ B(x chunk ks); causal masking
// is built into Afrag's zeroed d<0 entries.
__global__ __launch_bounds__(256) void conv_mfma(const u16* __restrict__ xtcT,
                                                 const u16* __restrict__ Afrag,
                                                 u16* __restrict__ xtb) {
  const int b = blockIdx.x;            // 0..255
  const int tid = threadIdx.x;
  const int w = tid >> 6, l = tid & 63;
  const int c = b >> 2;                // channel 0..63
  const int ltg = (b & 3) * 4 + w;     // 0..15 (group of 4 l-tiles)

  const u16* Ab = Afrag + (size_t)c * 32768 + ((l & 15) * 4 + (l >> 4)) * 8;
  const u16* Bb = xtcT + (size_t)c * 16384 + (l & 15) * 1024 + (l >> 4) * 8;

  f32x4 acc[4] = {};
  const int nks = 2 * ltg + 2;
  for (int ks = 0; ks < nks; ++ks) {
    const bf16x8 Bf = *(const bf16x8*)(Bb + 32 * ks);
#pragma unroll
    for (int m = 0; m < 4; ++m) {
      const int d16 = 4 * ltg + m - 2 * ks;
      if (d16 >= 0) {
        const bf16x8 Af = *(const bf16x8*)(Ab + d16 * 512);
        acc[m] = __builtin_amdgcn_mfma_f32_16x16x32_bf16(Af, Bf, acc[m], 0, 0, 0);
      }
    }
  }

  const int j = l & 15;                // head (cols 12..15 discarded)
  if (j < 12) {
#pragma unroll
    for (int m = 0; m < 4; ++m) {
      const int row0 = (4 * ltg + m) * 16 + ((l >> 4) << 2);
#pragma unroll
      for (int r = 0; r < 4; ++r)
        xtb[(size_t)(row0 + r) * DM + j * 64 + c] = f2b(acc[m][r]);
    }
  }
}

// ---------------------------------------------------------------------------
// K2: FUSED q,k,v GEMM — A-tile staged once per K-step, reused for 3 B's.
// grid 192 linear, block 256. Unchanged (passing).
__global__ __launch_bounds__(256) void qkv_mfma(const u16* __restrict__ xtb,
                                                const u16* __restrict__ wT,
                                                const float* __restrict__ bq,
                                                const float* __restrict__ bk,
                                                const float* __restrict__ bv,
                                                float* __restrict__ qo,
                                                float* __restrict__ ko,
                                                float* __restrict__ vo) {
  const int b = blockIdx.x;           // 0..191
  const int xcd = b & 7, j = b >> 3;  // j 0..23
  const int rt = (xcd & 3) * 4 + j / 6;
  const int ct = (xcd >> 2) * 6 + j % 6;

  __shared__ u16 As[64 * 64];         // 8 KB
  __shared__ u16 Bs[3][64 * 64];      // 24 KB

  const int tid = threadIdx.x, w = tid >> 6, l = tid & 63;
  const int wr = w >> 1, wc = w & 1;

  const int srow1 = tid >> 3, sc16 = tid & 7;
  const int c16L1 = sc16 ^ (srow1 & 7);
  const int srow2 = srow1 + 32;
  const int c16L2 = sc16 ^ (srow2 & 7);

  const u16* Ag1 = xtb + (size_t)(rt * 64 + srow1) * DM + c16L1 * 8;
  const u16* Ag2 = xtb + (size_t)(rt * 64 + srow2) * DM + c16L2 * 8;

  char* lA = (char*)As + w * 1024;

  f32x4 acc[3][2][2] = {};
  for (int kb = 0; kb < DM; kb += 64) {
    gld16(Ag1 + kb, lA);
    gld16(Ag2 + kb, lA + 4096);
#pragma unroll
    for (int z = 0; z < 3; ++z) {
      const u16* wz = wT + (size_t)z * WSZ;
      const u16* Bg1 = wz + (size_t)(ct * 64 + srow1) * DM + c16L1 * 8;
      const u16* Bg2 = wz + (size_t)(ct * 64 + srow2) * DM + c16L2 * 8;
      char* lB = (char*)Bs[z] + w * 1024;
      gld16(Bg1 + kb, lB);
      gld16(Bg2 + kb, lB + 4096);
    }
    __syncthreads();
#pragma unroll
    for (int kk = 0; kk < 2; ++kk) {
      bf16x8 a[2];
#pragma unroll
      for (int ar = 0; ar < 2; ++ar) {
        const int row = wr * 32 + ar * 16 + (l & 15);
        const int c16 = ((kk << 2) + (l >> 4)) ^ (row & 7);
        a[ar] = *(const bf16x8*)((char*)As + row * 128 + c16 * 16);
      }
#pragma unroll
      for (int z = 0; z < 3; ++z) {
        bf16x8 bb[2];
#pragma unroll
        for (int bc = 0; bc < 2; ++bc) {
          const int col = wc * 32 + bc * 16 + (l & 15);
          const int c16 = ((kk << 2) + (l >> 4)) ^ (col & 7);
          bb[bc] = *(const bf16x8*)((char*)Bs[z] + col * 128 + c16 * 16);
        }
#pragma unroll
        for (int ar = 0; ar < 2; ++ar)
#pragma unroll
          for (int bc = 0; bc < 2; ++bc)
            acc[z][ar][bc] = __builtin_amdgcn_mfma_f32_16x16x32_bf16(
                a[ar], bb[bc], acc[z][ar][bc], 0, 0, 0);
      }
    }
    __syncthreads();
  }

  const float* biasArr[3] = {bq, bk, bv};
  float* outArr[3] = {qo, ko, vo};
  const int rbase = rt * 64 + wr * 32 + ((l >> 4) << 2);
  const int cb = wc * 32 + (l & 15);
#pragma unroll
  for (int z = 0; z < 3; ++z) {
    const float* bias = biasArr[z];
    float* out = outArr[z];
#pragma unroll
    for (int ar = 0; ar < 2; ++ar)
#pragma unroll
      for (int bc = 0; bc < 2; ++bc) {
        const int col = cb + bc * 16;
        const float bbv = bias[ct * 64 + col];
#pragma unroll
        for (int r = 0; r < 4; ++r)
          out[((size_t)ct * LS + rbase + ar * 16 + r) * HD + col] =
              acc[z][ar][bc][r] + bbv;
      }
  }
}

// ---------------------------------------------------------------------------
// K6: y = lerpb @ wo + b, 64x64 tile MFMA. grid 192 linear. Unchanged (passing).
__global__ __launch_bounds__(256) void out_mfma(const u16* __restrict__ lerpb,
                                                const u16* __restrict__ woT,
                                                const float* __restrict__ bias,
                                                float* __restrict__ out) {
  const int b = blockIdx.x;
  const int xcd = b & 7, j = b >> 3;
  const int unit = xcd * 3 + (j >> 3), sub = j & 7;
  const int ct = unit >> 1, rt = (unit & 1) * 8 + sub;

  __shared__ u16 As[64 * 64];
  __shared__ u16 Bs[64 * 64];

  const int tid = threadIdx.x, w = tid >> 6, l = tid & 63;
  const int wr = w >> 1, wc = w & 1;

  const int srow1 = tid >> 3, sc16 = tid & 7;
  const int c16L1 = sc16 ^ (srow1 & 7);
  const int srow2 = srow1 + 32;
  const int c16L2 = sc16 ^ (srow2 & 7);

  const u16* Ag1 = lerpb + (size_t)(rt * 64 + srow1) * DM + c16L1 * 8;
  const u16* Ag2 = lerpb + (size_t)(rt * 64 + srow2) * DM + c16L2 * 8;
  const u16* Bg1 = woT + (size_t)(ct * 64 + srow1) * DM + c16L1 * 8;
  const u16* Bg2 = woT + (size_t)(ct * 64 + srow2) * DM + c16L2 * 8;

  char* lA = (char*)As + w * 1024;
  char* lB = (char*)Bs + w * 1024;

  f32x4 acc[2][2] = {};
  for (int kb = 0; kb < DM; kb += 64) {
    gld16(Ag1 + kb, lA);
    gld16(Ag2 + kb, lA + 4096);
    gld16(Bg1 + kb, lB);
    gld16(Bg2 + kb, lB + 4096);
    __syncthreads();
#pragma unroll
    for (int kk = 0; kk < 2; ++kk) {
      bf16x8 a[2], bb[2];
#pragma unroll
      for (int ar = 0; ar < 2; ++ar) {
        const int row = wr * 32 + ar * 16 + (l & 15);
        const int c16 = ((kk << 2) + (l >> 4)) ^ (row & 7);
        a[ar] = *(const bf16x8*)((char*)As + row * 128 + c16 * 16);
      }
#pragma unroll
      for (int bc = 0; bc < 2; ++bc) {
        const int col = wc * 32 + bc * 16 + (l & 15);
        const int c16 = ((kk << 2) + (l >> 4)) ^ (col & 7);
        bb[bc] = *(const bf16x8*)((char*)Bs + col * 128 + c16 * 16);
      }
#pragma unroll
      for (int ar = 0; ar < 2; ++ar)
#pragma unroll
        for (int bc = 0; bc < 2; ++bc)
          acc[ar][bc] = __builtin_amdgcn_mfma_f32_16x16x32_bf16(
              a[ar], bb[bc], acc[ar][bc], 0, 0, 0);
    }
    __syncthreads();
  }

  const int rbase = rt * 64 + wr * 32 + ((l >> 4) << 2);
  const int cb = wc * 32 + (l & 15);
#pragma unroll
  for (int ar = 0; ar < 2; ++ar)
#pragma unroll
    for (int bc = 0; bc < 2; ++bc) {
      const int col = ct * 64 + cb + bc * 16;
      const float bbv = bias[col];
#pragma unroll
      for (int r = 0; r < 4; ++r)
        out[(size_t)(rbase + ar * 16 + r) * DM + col] = acc[ar][bc][r] + bbv;
    }
}

// ---------------------------------------------------------------------------
// K3+K5a FUSED: l2norm + sim + gates + state outer product + NE.
// grid (NTL=64, NH), block 256. Unchanged (passing).
__global__ __launch_bounds__(256) void nsg_state_kernel(
    float* __restrict__ q, float* __restrict__ k, float* __restrict__ v,
    const float* __restrict__ wg, const float* __restrict__ wgb,
    const float* __restrict__ qk_scale, const float* __restrict__ kv_scale,
    float* __restrict__ sim, float* __restrict__ gates,
    float* __restrict__ states, float* __restrict__ nes) {
  const int j = blockIdx.x, head = blockIdx.y;
  const int s0 = j * SG;
  const int tid = threadIdx.x;
  const int wid = tid >> 6, lane = tid & 63;
  __shared__ alignas(16) float Vs[SG][68];
  __shared__ alignas(16) float Kg[SG][68];
  __shared__ float Es[SG];

  auto red = [](float x) {
#pragma unroll
    for (int o = 32; o; o >>= 1) x += __shfl_xor(x, o);
    return x;
  };

  const float qks = qk_scale[head], kvs = kv_scale[head], wb = wgb[0];
#pragma unroll
  for (int it = 0; it < 4; ++it) {
    const int rr = wid * 4 + it;
    const size_t idx = ((size_t)head * LS + s0 + rr) * HD + lane;
    float qv = q[idx], kv = k[idx], vv = v[idx];
    const float qn = fmaxf(sqrtf(red(qv * qv)), 1e-12f);
    const float kn = fmaxf(sqrtf(red(kv * kv)), 1e-12f);
    const float vn = fmaxf(sqrtf(red(vv * vv)), 1e-12f);
    qv /= qn; kv /= kn; vv /= vn;
    q[idx] = qv; k[idx] = kv; v[idx] = vv;
    const float s = red(qv * kv) * qks;
    Vs[rr][lane] = vv;
    float t = 0.f;
#pragma unroll 8
    for (int p = 0; p < 64; ++p) t = fmaf(Vs[rr][p], wg[p * 64 + lane], t);
    float gl = red(t * kv) * kvs + wb;
    gl = gl > 0.f ? gl : ALPHAF * gl;
    const float g = gl * gl + EPSF;
    Kg[rr][lane] = kv * g;
    if (lane == 0) {
      sim[head * LS + s0 + rr] = s;
      gates[head * LS + s0 + rr] = g;
      Es[rr] = expf(s);
    }
  }
  __syncthreads();

  const int p0 = (tid >> 4) * 4, n0 = (tid & 15) * 4;
  float acc[4][4] = {};
  for (int s = 0; s < SG; ++s) {
    const float4 ra = *(const float4*)&Vs[s][p0];
    const float4 rb = *(const float4*)&Kg[s][n0];
    const float av[4] = {ra.x, ra.y, ra.z, ra.w};
    const float bv[4] = {rb.x, rb.y, rb.z, rb.w};
#pragma unroll
    for (int i = 0; i < 4; ++i)
#pragma unroll
      for (int jj = 0; jj < 4; ++jj)
        acc[i][jj] = fmaf(av[i], bv[jj], acc[i][jj]);
  }
  float* Sout = states + (size_t)(head * NTL + j) * 4096;
#pragma unroll
  for (int i = 0; i < 4; ++i)
    *(float4*)&Sout[(p0 + i) * 64 + n0] =
        make_float4(acc[i][0], acc[i][1], acc[i][2], acc[i][3]);

  if (tid < HD) {
    float ne = 0.f;
#pragma unroll
    for (int s = 0; s < SG; ++s) ne = fmaf(Es[s], Vs[s][tid], ne);
    nes[(size_t)(head * NTL + j) * HD + tid] = ne;
  }
}

// ---------------------------------------------------------------------------
// K4+K5b: scalar shuffle-scans (chunk 0 only) + state prefix over 4 chunks
// per head (1 float/thread, coalesced). grid (NH, 4), block 1024. Unchanged.
__global__ __launch_bounds__(1024) void scan_prefix_kernel(
    const float* __restrict__ sim, const float* __restrict__ gates,
    float* __restrict__ m_s, float* __restrict__ Sraw, float* __restrict__ g_s,
    float* __restrict__ states, float* __restrict__ nes) {
  const int head = blockIdx.x, chunk = blockIdx.y;
  const int tid = threadIdx.x, lane = tid & 63, wid = tid >> 6;

  if (chunk == 0) {
    __shared__ float wm[16], wS[16], wg2[16];
    const float sv = sim[head * LS + tid];
    float m = sv, S = expf(sv), g = gates[head * LS + tid];
#pragma unroll
    for (int off = 1; off < 64; off <<= 1) {
      const float pm = __shfl_up(m, off);
      const float pS = __shfl_up(S, off);
      const float pg = __shfl_up(g, off);
      if (lane >= off) { m = fmaxf(m, pm); S += pS; g += pg; }
    }
    if (lane == 63) { wm[wid] = m; wS[wid] = S; wg2[wid] = g; }
    __syncthreads();
    for (int w2 = 0; w2 < wid; ++w2) {
      m = fmaxf(m, wm[w2]); S += wS[w2]; g += wg2[w2];
    }
    m_s[head * LS + tid] = m;
    Sraw[head * LS + tid] = S;
    g_s[head * LS + tid] = g;

    if (tid < HD) {
      float a = 0.f;
      float* nb = nes + (size_t)head * NTL * HD + tid;
#pragma unroll 4
      for (int jj = 0; jj < NTL; ++jj) {
        float* p = nb + (size_t)jj * HD;
        const float t = *p;
        *p = a;
        a += t;
      }
    }
  }

  {
    float a = 0.f;
    float* base = states + (size_t)head * NTL * 4096 + chunk * 1024 + tid;
#pragma unroll 4
    for (int jj = 0; jj < NTL; ++jj) {
      float* p = base + (size_t)jj * 4096;
      const float t = *p;
      *p = a;
      a += t;
    }
  }
}

// ---------------------------------------------------------------------------
// K5c: apply + epilogue; writes lerp in bf16. grid (NTL, NH), block 256.
// Unchanged (passing).
__global__ __launch_bounds__(256) void apply_kernel(const float* __restrict__ q,
                                                    const float* __restrict__ k,
                                                    const float* __restrict__ v,
                                                    const float* __restrict__ sim,
                                                    const float* __restrict__ gates,
                                                    const float* __restrict__ m_s,
                                                    const float* __restrict__ Sraw,
                                                    const float* __restrict__ g_s,
                                                    const float* __restrict__ states,
                                                    const float* __restrict__ nes,
                                                    const float* __restrict__ kv_scale,
                                                    u16* __restrict__ lerpb) {
  const int bt = blockIdx.x, head = blockIdx.y;
  const int t0 = bt * SG;
  const int tid = threadIdx.x;
  __shared__ alignas(16) float Ps[64][68];
  __shared__ alignas(16) float Qs[SG][68];
  __shared__ alignas(16) float Vs[SG][68];
  __shared__ alignas(16) float Ks[SG][68];
  __shared__ alignas(16) float NEp[64];
  __shared__ float Ag[SG][SG + 1];
  __shared__ float Es[SG], Gs[SG];

  const float* Pg = states + (size_t)(head * NTL + bt) * 4096;
#pragma unroll
  for (int rep = 0; rep < 4; ++rep) {
    const int lin = rep * 1024 + tid * 4;
    *(float4*)&Ps[lin >> 6][lin & 63] = *(const float4*)(Pg + lin);
  }
  {
    const int r = tid >> 4, c = (tid & 15) * 4;
    const size_t rowbase = ((size_t)head * LS + t0 + r) * HD;
    *(float4*)&Qs[r][c] = *(const float4*)(q + rowbase + c);
    *(float4*)&Ks[r][c] = *(const float4*)(k + rowbase + c);
    *(float4*)&Vs[r][c] = *(const float4*)(v + rowbase + c);
  }
  if (tid < SG) {
    Es[tid] = expf(sim[head * LS + t0 + tid]);
    Gs[tid] = gates[head * LS + t0 + tid];
  }
  if (tid < HD) NEp[tid] = nes[(size_t)(head * NTL + bt) * HD + tid];
  __syncthreads();

  {
    const int t = tid >> 4, s = tid & 15;
    float a = 0.f;
    if (s <= t) {
#pragma unroll
      for (int p = 0; p < 64; p += 4) {
        const float4 q4 = *(const float4*)&Qs[t][p];
        const float4 v4 = *(const float4*)&Vs[s][p];
        a = fmaf(q4.x, v4.x, a); a = fmaf(q4.y, v4.y, a);
        a = fmaf(q4.z, v4.z, a); a = fmaf(q4.w, v4.w, a);
      }
      a *= Gs[s];
    }
    Ag[t][s] = a;
  }
  __syncthreads();

  const int r = tid >> 4, c0 = (tid & 15) * 4;
  float4 O = make_float4(0.f, 0.f, 0.f, 0.f);
#pragma unroll 8
  for (int p = 0; p < 64; ++p) {
    const float qv = Qs[r][p];
    const float4 p4 = *(const float4*)&Ps[p][c0];
    O.x = fmaf(qv, p4.x, O.x); O.y = fmaf(qv, p4.y, O.y);
    O.z = fmaf(qv, p4.z, O.z); O.w = fmaf(qv, p4.w, O.w);
  }
  float4 Nn = *(const float4*)&NEp[c0];
  for (int s = 0; s <= r; ++s) {
    const float ag = Ag[r][s];
    const float es = Es[s];
    const float4 k4 = *(const float4*)&Ks[s][c0];
    const float4 v4 = *(const float4*)&Vs[s][c0];
    O.x = fmaf(ag, k4.x, O.x); O.y = fmaf(ag, k4.y, O.y);
    O.z = fmaf(ag, k4.z, O.z); O.w = fmaf(ag, k4.w, O.w);
    Nn.x = fmaf(es, v4.x, Nn.x); Nn.y = fmaf(es, v4.y, Nn.y);
    Nn.z = fmaf(es, v4.z, Nn.z); Nn.w = fmaf(es, v4.w, Nn.w);
  }

  const int t = t0 + r;
  const float m  = m_s[head * LS + t];
  const float em = expf(-m);
  const float ss = Sraw[head * LS + t] * em;
  const float inv = 1.f / (ss + EPSF);
  const float sw  = expf(sim[head * LS + t] - m) * inv;
  const float gi  = kv_scale[head] / (g_s[head * LS + t] + EPSF);
  const float ei  = em * inv;
  float rx, ry, rz, rw;
  { const float cx = O.x * gi, la = Nn.x * ei; rx = cx + (la - cx) * sw; }
  { const float cx = O.y * gi, la = Nn.y * ei; ry = cx + (la - cx) * sw; }
  { const float cx = O.z * gi, la = Nn.z * ei; rz = cx + (la - cx) * sw; }
  { const float cx = O.w * gi, la = Nn.w * ei; rw = cx + (la - cx) * sw; }
  ushort4 ob;
  ob.x = f2b(rx); ob.y = f2b(ry); ob.z = f2b(rz); ob.w = f2b(rw);
  *(ushort4*)&lerpb[(size_t)t * DM + head * HD + c0] = ob;
}

// ---------------------------------------------------------------------------
extern "C" void kernel_launch(void* const* d_in, const int* in_sizes, int n_in,
                              void* d_out, int out_size, void* d_ws, size_t ws_size,
                              hipStream_t stream) {
  (void)in_sizes; (void)n_in; (void)out_size; (void)ws_size;
  const float* x        = (const float*)d_in[0];
  const float* filters  = (const float*)d_in[1];
  const float* wq_w     = (const float*)d_in[2];
  const float* wq_b     = (const float*)d_in[3];
  const float* wk_w     = (const float*)d_in[4];
  const float* wk_b     = (const float*)d_in[5];
  const float* wv_w     = (const float*)d_in[6];
  const float* wv_b     = (const float*)d_in[7];
  const float* wo_w     = (const float*)d_in[8];
  const float* wo_b     = (const float*)d_in[9];
  const float* wg_w     = (const float*)d_in[10];
  const float* wg_b     = (const float*)d_in[11];
  const float* qk_scale = (const float*)d_in[12];
  const float* kv_scale = (const float*)d_in[13];

  float* ws = (float*)d_ws;
  const size_t NT = (size_t)LS * DM;  // 786432
  float* q     = ws;
  float* k     = ws + NT;
  float* v     = ws + 2 * NT;
  float* sim   = ws + 3 * NT;
  float* gates = sim + NH * LS;
  float* m_s   = gates + NH * LS;
  float* Sraw  = m_s + NH * LS;
  float* g_s   = Sraw + NH * LS;
  float* states = g_s + NH * LS;                       // 12*64*4096 f32
  float* nes    = states + (size_t)NH * NTL * 4096;    // 12*64*64 f32
  u16*   xtb    = (u16*)(nes + (size_t)NH * NTL * HD); // NT bf16
  u16*   wT     = xtb + NT;                            // 4 * WSZ bf16
  u16*   lerpb  = wT + 4 * (size_t)WSZ;                // NT bf16
  u16*   xtcT   = lerpb + NT;                          // 64*16*1024 bf16
  u16*   Afrag  = xtcT + (size_t)64 * 16 * 1024;       // 64*64*512 bf16

  prep_kernel<<<dim3(832), 256, 0, stream>>>(
      x, filters, wq_w, wk_w, wv_w, wo_w, wT, xtcT, Afrag);
  conv_mfma<<<dim3(256), 256, 0, stream>>>(xtcT, Afrag, xtb);
  qkv_mfma<<<dim3(192), 256, 0, stream>>>(xtb, wT, wq_b, wk_b, wv_b, q, k, v);
  nsg_state_kernel<<<dim3(NTL, NH), 256, 0, stream>>>(
      q, k, v, wg_w, wg_b, qk_scale, kv_scale, sim, gates, states, nes);
  scan_prefix_kernel<<<dim3(NH, 4), 1024, 0, stream>>>(
      sim, gates, m_s, Sraw, g_s, states, nes);
  apply_kernel<<<dim3(NTL, NH), 256, 0, stream>>>(
      q, k, v, sim, gates, m_s, Sraw, g_s, states, nes, kv_scale, lerpb);
  out_mfma<<<dim3(192), 256, 0, stream>>>(
      lerpb, wT + 3 * (size_t)WSZ, wo_b, (float*)d_out);
}

// Round 17
// 101.129 us; speedup vs baseline: 1.2327x; 1.2327x over previous
//
#include <hip/hip_runtime.h>
#include <hip/hip_bf16.h>

constexpr int LS = 1024;   // sequence length
constexpr int DM = 768;    // model dim
constexpr int NH = 12;     // heads
constexpr int HD = 64;     // head dim
constexpr float EPSF = 1e-5f;
constexpr float ALPHAF = 0.01f;

constexpr int SG = 16;             // state granularity (rows per tile)
constexpr int NTL = LS / SG;       // 64 tiles per head
constexpr int WSZ = DM * DM;       // 589824 elements per weight matrix
constexpr int NPAR = 8;            // conv parity split

typedef unsigned short u16;
typedef __attribute__((ext_vector_type(8))) short bf16x8;
typedef __attribute__((ext_vector_type(8))) unsigned short u16x8;
typedef __attribute__((ext_vector_type(4))) float f32x4;

__device__ __forceinline__ u16 f2b(float f) {
  unsigned u = __float_as_uint(f);
  u += 0x7FFFu + ((u >> 16) & 1u);   // round-to-nearest-even
  return (u16)(u >> 16);
}
__device__ __forceinline__ float b2f(u16 b) {
  return __uint_as_float((unsigned)b << 16);
}

// async global->LDS, 16B per lane; LDS dest is wave-uniform base + lane*16
__device__ __forceinline__ void gld16(const u16* g, void* l) {
  __builtin_amdgcn_global_load_lds(
      (const __attribute__((address_space(1))) void*)g,
      (__attribute__((address_space(3))) void*)l, 16, 0, 0);
}

// ---------------------------------------------------------------------------
// K1: FUSED causal-conv (parity-8 banded stencil, bf16 partials) + weight
// transpose/bf16 pack. grid 2112 linear, block 256, dynamic LDS 28672 B.
__global__ __launch_bounds__(256) void conv_txw_kernel(
    const float* __restrict__ x, const float* __restrict__ f,
    const float* __restrict__ wq, const float* __restrict__ wk,
    const float* __restrict__ wv, const float* __restrict__ wo,
    u16* __restrict__ wT, u16* __restrict__ pbase) {
  extern __shared__ char smem[];
  const int b = blockIdx.x;
  const int tid = threadIdx.x;

  if (b >= 1536) {
    // ---- txw: wT[z][n][k] = bf16(w[k][n]) ----
    const int b2 = b - 1536;
    const int kb = (b2 % 12) * 64, nb = ((b2 / 12) % 12) * 64, z = b2 / 144;
    const float* src = (z == 0) ? wq : (z == 1) ? wk : (z == 2) ? wv : wo;
    u16* dst = wT + (size_t)z * WSZ;
    float (*T)[65] = (float(*)[65])smem;
#pragma unroll
    for (int rep = 0; rep < 4; ++rep) {
      const int r = rep * 16 + (tid >> 4);
      const int c4 = (tid & 15) * 4;
      const float4 v4 = *(const float4*)(src + (size_t)(kb + r) * DM + nb + c4);
      T[r][c4] = v4.x; T[r][c4 + 1] = v4.y; T[r][c4 + 2] = v4.z; T[r][c4 + 3] = v4.w;
    }
    __syncthreads();
#pragma unroll
    for (int rep = 0; rep < 4; ++rep) {
      const int n = rep * 16 + (tid >> 4);
      const int k4 = (tid & 15) * 4;
      ushort4 o;
      o.x = f2b(T[k4 + 0][n]); o.y = f2b(T[k4 + 1][n]);
      o.z = f2b(T[k4 + 2][n]); o.w = f2b(T[k4 + 3][n]);
      *(ushort4*)(dst + (size_t)(nb + n) * DM + kb + k4) = o;
    }
    return;
  }

  // ---- conv ----
  const int i    = b & 15;
  const int head = (b >> 4) % 12;
  const int par  = b / 192;
  const int c    = tid & 63;
  const int sg   = tid >> 6;
  const int tbase = i * 64;
  const int l0w   = tbase + sg * 16;
  u16* __restrict__ xt_p = pbase + (size_t)par * LS * DM;

  float4 (*Xs2)[64] = (float4(*)[64])smem;  // groups 0..27, pads zeroed

  {
    const float4 z4 = make_float4(0.f, 0.f, 0.f, 0.f);
#pragma unroll
    for (int k = 0; k < 3; ++k) {
      const int lin = k * 256 + tid;
      const int g   = lin >> 6;
      const int cc  = lin & 63;
      const int grp = (g < 4) ? g : (16 + g);
      Xs2[grp][cc] = z4;
    }
  }

  float acc[16];
#pragma unroll
  for (int t = 0; t < 16; ++t) acc[t] = 0.f;

  const float* xg   = x + head * HD + c;
  const float* fcol = f + c;

  for (int j = par; j <= i; j += NPAR) {
    const int sbase = j * 64;
    const int b0 = (j < i) ? (tbase - sbase - 64) : 0;
#pragma unroll
    for (int k = 0; k < 4; ++k) {
      const int m  = sg + 4 * k;
      const int ss = 4 * m;
      float4 v4;
      v4.x = xg[(sbase + ss + 0) * DM];
      v4.y = xg[(sbase + ss + 1) * DM];
      v4.z = xg[(sbase + ss + 2) * DM];
      v4.w = xg[(sbase + ss + 3) * DM];
      Xs2[4 + m][c] = v4;
    }
    __syncthreads();

    const int dstart = (j < i) ? (b0 + sg * 16) : 0;
    const int nsteps = (j < i) ? 5 : (sg + 1);
    for (int k = 0; k < nsteps; ++k) {
      const int d0    = dstart + 16 * k;
      const int rbase = l0w - d0 - sbase;
      float fr[16];
#pragma unroll
      for (int m = 0; m < 16; ++m) fr[m] = fcol[(d0 + m) * HD];
      float xw[32];
      const int xgb = rbase >> 2;
#pragma unroll
      for (int m = 0; m < 8; ++m) {
        const float4 v4 = Xs2[xgb + m][c];
        xw[4 * m + 0] = v4.x; xw[4 * m + 1] = v4.y;
        xw[4 * m + 2] = v4.z; xw[4 * m + 3] = v4.w;
      }
#pragma unroll
      for (int li = 0; li < 16; ++li)
#pragma unroll
        for (int dd = 0; dd < 16; ++dd)
          acc[li] = fmaf(fr[dd], xw[li - dd + 16], acc[li]);
    }
    __syncthreads();
  }

#pragma unroll
  for (int li = 0; li < 16; ++li)
    xt_p[(size_t)(l0w + li) * DM + head * HD + c] = f2b(acc[li]);
}

// ---------------------------------------------------------------------------
// K1b: xtb = bf16(sum of 8 bf16 partials). grid 384, block 256.
__global__ __launch_bounds__(256) void pack_xt(const u16* __restrict__ pbase,
                                               u16* __restrict__ xtb) {
  const size_t NT = (size_t)LS * DM;
  const size_t i = ((size_t)blockIdx.x * 256 + threadIdx.x) * 8;
  float s[8] = {};
#pragma unroll
  for (int p = 0; p < NPAR; ++p) {
    const u16x8 v8 = *(const u16x8*)(pbase + p * NT + i);
#pragma unroll
    for (int e = 0; e < 8; ++e) s[e] += b2f(v8[e]);
  }
  u16x8 o;
#pragma unroll
  for (int e = 0; e < 8; ++e) o[e] = f2b(s[e]);
  *(u16x8*)(xtb + i) = o;
}

// ---------------------------------------------------------------------------
// K2: FUSED q,k,v GEMM — one block computes all three z for one (head, rt):
// A-tile staged once per K-step, reused for 3 B's. grid 192 linear, block 256.
__global__ __launch_bounds__(256) void qkv_mfma(const u16* __restrict__ xtb,
                                                const u16* __restrict__ wT,
                                                const float* __restrict__ bq,
                                                const float* __restrict__ bk,
                                                const float* __restrict__ bv,
                                                float* __restrict__ qo,
                                                float* __restrict__ ko,
                                                float* __restrict__ vo) {
  const int b = blockIdx.x;           // 0..191
  const int xcd = b & 7, j = b >> 3;  // j 0..23
  const int rt = (xcd & 3) * 4 + j / 6;
  const int ct = (xcd >> 2) * 6 + j % 6;

  __shared__ u16 As[64 * 64];         // 8 KB
  __shared__ u16 Bs[3][64 * 64];      // 24 KB

  const int tid = threadIdx.x, w = tid >> 6, l = tid & 63;
  const int wr = w >> 1, wc = w & 1;

  const int srow1 = tid >> 3, sc16 = tid & 7;
  const int c16L1 = sc16 ^ (srow1 & 7);
  const int srow2 = srow1 + 32;
  const int c16L2 = sc16 ^ (srow2 & 7);

  const u16* Ag1 = xtb + (size_t)(rt * 64 + srow1) * DM + c16L1 * 8;
  const u16* Ag2 = xtb + (size_t)(rt * 64 + srow2) * DM + c16L2 * 8;

  char* lA = (char*)As + w * 1024;

  f32x4 acc[3][2][2] = {};
  for (int kb = 0; kb < DM; kb += 64) {
    gld16(Ag1 + kb, lA);
    gld16(Ag2 + kb, lA + 4096);
#pragma unroll
    for (int z = 0; z < 3; ++z) {
      const u16* wz = wT + (size_t)z * WSZ;
      const u16* Bg1 = wz + (size_t)(ct * 64 + srow1) * DM + c16L1 * 8;
      const u16* Bg2 = wz + (size_t)(ct * 64 + srow2) * DM + c16L2 * 8;
      char* lB = (char*)Bs[z] + w * 1024;
      gld16(Bg1 + kb, lB);
      gld16(Bg2 + kb, lB + 4096);
    }
    __syncthreads();
#pragma unroll
    for (int kk = 0; kk < 2; ++kk) {
      bf16x8 a[2];
#pragma unroll
      for (int ar = 0; ar < 2; ++ar) {
        const int row = wr * 32 + ar * 16 + (l & 15);
        const int c16 = ((kk << 2) + (l >> 4)) ^ (row & 7);
        a[ar] = *(const bf16x8*)((char*)As + row * 128 + c16 * 16);
      }
#pragma unroll
      for (int z = 0; z < 3; ++z) {
        bf16x8 bb[2];
#pragma unroll
        for (int bc = 0; bc < 2; ++bc) {
          const int col = wc * 32 + bc * 16 + (l & 15);
          const int c16 = ((kk << 2) + (l >> 4)) ^ (col & 7);
          bb[bc] = *(const bf16x8*)((char*)Bs[z] + col * 128 + c16 * 16);
        }
#pragma unroll
        for (int ar = 0; ar < 2; ++ar)
#pragma unroll
          for (int bc = 0; bc < 2; ++bc)
            acc[z][ar][bc] = __builtin_amdgcn_mfma_f32_16x16x32_bf16(
                a[ar], bb[bc], acc[z][ar][bc], 0, 0, 0);
      }
    }
    __syncthreads();
  }

  const float* biasArr[3] = {bq, bk, bv};
  float* outArr[3] = {qo, ko, vo};
  const int rbase = rt * 64 + wr * 32 + ((l >> 4) << 2);
  const int cb = wc * 32 + (l & 15);
#pragma unroll
  for (int z = 0; z < 3; ++z) {
    const float* bias = biasArr[z];
    float* out = outArr[z];
#pragma unroll
    for (int ar = 0; ar < 2; ++ar)
#pragma unroll
      for (int bc = 0; bc < 2; ++bc) {
        const int col = cb + bc * 16;
        const float bbv = bias[ct * 64 + col];
#pragma unroll
        for (int r = 0; r < 4; ++r)
          out[((size_t)ct * LS + rbase + ar * 16 + r) * HD + col] =
              acc[z][ar][bc][r] + bbv;
      }
  }
}

// ---------------------------------------------------------------------------
// K6: y = lerpb @ wo + b, 64x64 tile MFMA. grid 192 linear.
__global__ __launch_bounds__(256) void out_mfma(const u16* __restrict__ lerpb,
                                                const u16* __restrict__ woT,
                                                const float* __restrict__ bias,
                                                float* __restrict__ out) {
  const int b = blockIdx.x;
  const int xcd = b & 7, j = b >> 3;
  const int unit = xcd * 3 + (j >> 3), sub = j & 7;
  const int ct = unit >> 1, rt = (unit & 1) * 8 + sub;

  __shared__ u16 As[64 * 64];
  __shared__ u16 Bs[64 * 64];

  const int tid = threadIdx.x, w = tid >> 6, l = tid & 63;
  const int wr = w >> 1, wc = w & 1;

  const int srow1 = tid >> 3, sc16 = tid & 7;
  const int c16L1 = sc16 ^ (srow1 & 7);
  const int srow2 = srow1 + 32;
  const int c16L2 = sc16 ^ (srow2 & 7);

  const u16* Ag1 = lerpb + (size_t)(rt * 64 + srow1) * DM + c16L1 * 8;
  const u16* Ag2 = lerpb + (size_t)(rt * 64 + srow2) * DM + c16L2 * 8;
  const u16* Bg1 = woT + (size_t)(ct * 64 + srow1) * DM + c16L1 * 8;
  const u16* Bg2 = woT + (size_t)(ct * 64 + srow2) * DM + c16L2 * 8;

  char* lA = (char*)As + w * 1024;
  char* lB = (char*)Bs + w * 1024;

  f32x4 acc[2][2] = {};
  for (int kb = 0; kb < DM; kb += 64) {
    gld16(Ag1 + kb, lA);
    gld16(Ag2 + kb, lA + 4096);
    gld16(Bg1 + kb, lB);
    gld16(Bg2 + kb, lB + 4096);
    __syncthreads();
#pragma unroll
    for (int kk = 0; kk < 2; ++kk) {
      bf16x8 a[2], bb[2];
#pragma unroll
      for (int ar = 0; ar < 2; ++ar) {
        const int row = wr * 32 + ar * 16 + (l & 15);
        const int c16 = ((kk << 2) + (l >> 4)) ^ (row & 7);
        a[ar] = *(const bf16x8*)((char*)As + row * 128 + c16 * 16);
      }
#pragma unroll
      for (int bc = 0; bc < 2; ++bc) {
        const int col = wc * 32 + bc * 16 + (l & 15);
        const int c16 = ((kk << 2) + (l >> 4)) ^ (col & 7);
        bb[bc] = *(const bf16x8*)((char*)Bs + col * 128 + c16 * 16);
      }
#pragma unroll
      for (int ar = 0; ar < 2; ++ar)
#pragma unroll
        for (int bc = 0; bc < 2; ++bc)
          acc[ar][bc] = __builtin_amdgcn_mfma_f32_16x16x32_bf16(
              a[ar], bb[bc], acc[ar][bc], 0, 0, 0);
    }
    __syncthreads();
  }

  const int rbase = rt * 64 + wr * 32 + ((l >> 4) << 2);
  const int cb = wc * 32 + (l & 15);
#pragma unroll
  for (int ar = 0; ar < 2; ++ar)
#pragma unroll
    for (int bc = 0; bc < 2; ++bc) {
      const int col = ct * 64 + cb + bc * 16;
      const float bbv = bias[col];
#pragma unroll
      for (int r = 0; r < 4; ++r)
        out[(size_t)(rbase + ar * 16 + r) * DM + col] = acc[ar][bc][r] + bbv;
    }
}

// ---------------------------------------------------------------------------
// K3+K5a FUSED: l2norm + sim + gates + state outer product + NE.
// grid (NTL=64, NH), block 256.
__global__ __launch_bounds__(256) void nsg_state_kernel(
    float* __restrict__ q, float* __restrict__ k, float* __restrict__ v,
    const float* __restrict__ wg, const float* __restrict__ wgb,
    const float* __restrict__ qk_scale, const float* __restrict__ kv_scale,
    float* __restrict__ sim, float* __restrict__ gates,
    float* __restrict__ states, float* __restrict__ nes) {
  const int j = blockIdx.x, head = blockIdx.y;
  const int s0 = j * SG;
  const int tid = threadIdx.x;
  const int wid = tid >> 6, lane = tid & 63;
  __shared__ alignas(16) float Vs[SG][68];
  __shared__ alignas(16) float Kg[SG][68];
  __shared__ float Es[SG];

  auto red = [](float x) {
#pragma unroll
    for (int o = 32; o; o >>= 1) x += __shfl_xor(x, o);
    return x;
  };

  const float qks = qk_scale[head], kvs = kv_scale[head], wb = wgb[0];
#pragma unroll
  for (int it = 0; it < 4; ++it) {
    const int rr = wid * 4 + it;
    const size_t idx = ((size_t)head * LS + s0 + rr) * HD + lane;
    float qv = q[idx], kv = k[idx], vv = v[idx];
    const float qn = fmaxf(sqrtf(red(qv * qv)), 1e-12f);
    const float kn = fmaxf(sqrtf(red(kv * kv)), 1e-12f);
    const float vn = fmaxf(sqrtf(red(vv * vv)), 1e-12f);
    qv /= qn; kv /= kn; vv /= vn;
    q[idx] = qv; k[idx] = kv; v[idx] = vv;
    const float s = red(qv * kv) * qks;
    Vs[rr][lane] = vv;
    float t = 0.f;
#pragma unroll 8
    for (int p = 0; p < 64; ++p) t = fmaf(Vs[rr][p], wg[p * 64 + lane], t);
    float gl = red(t * kv) * kvs + wb;
    gl = gl > 0.f ? gl : ALPHAF * gl;
    const float g = gl * gl + EPSF;
    Kg[rr][lane] = kv * g;
    if (lane == 0) {
      sim[head * LS + s0 + rr] = s;
      gates[head * LS + s0 + rr] = g;
      Es[rr] = expf(s);
    }
  }
  __syncthreads();

  const int p0 = (tid >> 4) * 4, n0 = (tid & 15) * 4;
  float acc[4][4] = {};
  for (int s = 0; s < SG; ++s) {
    const float4 ra = *(const float4*)&Vs[s][p0];
    const float4 rb = *(const float4*)&Kg[s][n0];
    const float av[4] = {ra.x, ra.y, ra.z, ra.w};
    const float bv[4] = {rb.x, rb.y, rb.z, rb.w};
#pragma unroll
    for (int i = 0; i < 4; ++i)
#pragma unroll
      for (int jj = 0; jj < 4; ++jj)
        acc[i][jj] = fmaf(av[i], bv[jj], acc[i][jj]);
  }
  float* Sout = states + (size_t)(head * NTL + j) * 4096;
#pragma unroll
  for (int i = 0; i < 4; ++i)
    *(float4*)&Sout[(p0 + i) * 64 + n0] =
        make_float4(acc[i][0], acc[i][1], acc[i][2], acc[i][3]);

  if (tid < HD) {
    float ne = 0.f;
#pragma unroll
    for (int s = 0; s < SG; ++s) ne = fmaf(Es[s], Vs[s][tid], ne);
    nes[(size_t)(head * NTL + j) * HD + tid] = ne;
  }
}

// ---------------------------------------------------------------------------
// K4+K5b: scalar shuffle-scans (chunk 0 only) + state prefix over 4 chunks
// per head (1 float/thread, coalesced). grid (NH, 4), block 1024.
__global__ __launch_bounds__(1024) void scan_prefix_kernel(
    const float* __restrict__ sim, const float* __restrict__ gates,
    float* __restrict__ m_s, float* __restrict__ Sraw, float* __restrict__ g_s,
    float* __restrict__ states, float* __restrict__ nes) {
  const int head = blockIdx.x, chunk = blockIdx.y;
  const int tid = threadIdx.x, lane = tid & 63, wid = tid >> 6;

  if (chunk == 0) {
    __shared__ float wm[16], wS[16], wg2[16];
    const float sv = sim[head * LS + tid];
    float m = sv, S = expf(sv), g = gates[head * LS + tid];
#pragma unroll
    for (int off = 1; off < 64; off <<= 1) {
      const float pm = __shfl_up(m, off);
      const float pS = __shfl_up(S, off);
      const float pg = __shfl_up(g, off);
      if (lane >= off) { m = fmaxf(m, pm); S += pS; g += pg; }
    }
    if (lane == 63) { wm[wid] = m; wS[wid] = S; wg2[wid] = g; }
    __syncthreads();
    for (int w2 = 0; w2 < wid; ++w2) {
      m = fmaxf(m, wm[w2]); S += wS[w2]; g += wg2[w2];
    }
    m_s[head * LS + tid] = m;
    Sraw[head * LS + tid] = S;
    g_s[head * LS + tid] = g;

    if (tid < HD) {
      float a = 0.f;
      float* nb = nes + (size_t)head * NTL * HD + tid;
#pragma unroll 4
      for (int jj = 0; jj < NTL; ++jj) {
        float* p = nb + (size_t)jj * HD;
        const float t = *p;
        *p = a;
        a += t;
      }
    }
  }

  {
    float a = 0.f;
    float* base = states + (size_t)head * NTL * 4096 + chunk * 1024 + tid;
#pragma unroll 4
    for (int jj = 0; jj < NTL; ++jj) {
      float* p = base + (size_t)jj * 4096;
      const float t = *p;
      *p = a;
      a += t;
    }
  }
}

// ---------------------------------------------------------------------------
// K5c: apply + epilogue; writes lerp in bf16. grid (NTL, NH), block 256.
__global__ __launch_bounds__(256) void apply_kernel(const float* __restrict__ q,
                                                    const float* __restrict__ k,
                                                    const float* __restrict__ v,
                                                    const float* __restrict__ sim,
                                                    const float* __restrict__ gates,
                                                    const float* __restrict__ m_s,
                                                    const float* __restrict__ Sraw,
                                                    const float* __restrict__ g_s,
                                                    const float* __restrict__ states,
                                                    const float* __restrict__ nes,
                                                    const float* __restrict__ kv_scale,
                                                    u16* __restrict__ lerpb) {
  const int bt = blockIdx.x, head = blockIdx.y;
  const int t0 = bt * SG;
  const int tid = threadIdx.x;
  __shared__ alignas(16) float Ps[64][68];
  __shared__ alignas(16) float Qs[SG][68];
  __shared__ alignas(16) float Vs[SG][68];
  __shared__ alignas(16) float Ks[SG][68];
  __shared__ alignas(16) float NEp[64];
  __shared__ float Ag[SG][SG + 1];
  __shared__ float Es[SG], Gs[SG];

  const float* Pg = states + (size_t)(head * NTL + bt) * 4096;
#pragma unroll
  for (int rep = 0; rep < 4; ++rep) {
    const int lin = rep * 1024 + tid * 4;
    *(float4*)&Ps[lin >> 6][lin & 63] = *(const float4*)(Pg + lin);
  }
  {
    const int r = tid >> 4, c = (tid & 15) * 4;
    const size_t rowbase = ((size_t)head * LS + t0 + r) * HD;
    *(float4*)&Qs[r][c] = *(const float4*)(q + rowbase + c);
    *(float4*)&Ks[r][c] = *(const float4*)(k + rowbase + c);
    *(float4*)&Vs[r][c] = *(const float4*)(v + rowbase + c);
  }
  if (tid < SG) {
    Es[tid] = expf(sim[head * LS + t0 + tid]);
    Gs[tid] = gates[head * LS + t0 + tid];
  }
  if (tid < HD) NEp[tid] = nes[(size_t)(head * NTL + bt) * HD + tid];
  __syncthreads();

  {
    const int t = tid >> 4, s = tid & 15;
    float a = 0.f;
    if (s <= t) {
#pragma unroll
      for (int p = 0; p < 64; p += 4) {
        const float4 q4 = *(const float4*)&Qs[t][p];
        const float4 v4 = *(const float4*)&Vs[s][p];
        a = fmaf(q4.x, v4.x, a); a = fmaf(q4.y, v4.y, a);
        a = fmaf(q4.z, v4.z, a); a = fmaf(q4.w, v4.w, a);
      }
      a *= Gs[s];
    }
    Ag[t][s] = a;
  }
  __syncthreads();

  const int r = tid >> 4, c0 = (tid & 15) * 4;
  float4 O = make_float4(0.f, 0.f, 0.f, 0.f);
#pragma unroll 8
  for (int p = 0; p < 64; ++p) {
    const float qv = Qs[r][p];
    const float4 p4 = *(const float4*)&Ps[p][c0];
    O.x = fmaf(qv, p4.x, O.x); O.y = fmaf(qv, p4.y, O.y);
    O.z = fmaf(qv, p4.z, O.z); O.w = fmaf(qv, p4.w, O.w);
  }
  float4 Nn = *(const float4*)&NEp[c0];
  for (int s = 0; s <= r; ++s) {
    const float ag = Ag[r][s];
    const float es = Es[s];
    const float4 k4 = *(const float4*)&Ks[s][c0];
    const float4 v4 = *(const float4*)&Vs[s][c0];
    O.x = fmaf(ag, k4.x, O.x); O.y = fmaf(ag, k4.y, O.y);
    O.z = fmaf(ag, k4.z, O.z); O.w = fmaf(ag, k4.w, O.w);
    Nn.x = fmaf(es, v4.x, Nn.x); Nn.y = fmaf(es, v4.y, Nn.y);
    Nn.z = fmaf(es, v4.z, Nn.z); Nn.w = fmaf(es, v4.w, Nn.w);
  }

  const int t = t0 + r;
  const float m  = m_s[head * LS + t];
  const float em = expf(-m);
  const float ss = Sraw[head * LS + t] * em;
  const float inv = 1.f / (ss + EPSF);
  const float sw  = expf(sim[head * LS + t] - m) * inv;
  const float gi  = kv_scale[head] / (g_s[head * LS + t] + EPSF);
  const float ei  = em * inv;
  float rx, ry, rz, rw;
  { const float cx = O.x * gi, la = Nn.x * ei; rx = cx + (la - cx) * sw; }
  { const float cx = O.y * gi, la = Nn.y * ei; ry = cx + (la - cx) * sw; }
  { const float cx = O.z * gi, la = Nn.z * ei; rz = cx + (la - cx) * sw; }
  { const float cx = O.w * gi, la = Nn.w * ei; rw = cx + (la - cx) * sw; }
  ushort4 ob;
  ob.x = f2b(rx); ob.y = f2b(ry); ob.z = f2b(rz); ob.w = f2b(rw);
  *(ushort4*)&lerpb[(size_t)t * DM + head * HD + c0] = ob;
}

// ---------------------------------------------------------------------------
extern "C" void kernel_launch(void* const* d_in, const int* in_sizes, int n_in,
                              void* d_out, int out_size, void* d_ws, size_t ws_size,
                              hipStream_t stream) {
  (void)in_sizes; (void)n_in; (void)out_size; (void)ws_size;
  const float* x        = (const float*)d_in[0];
  const float* filters  = (const float*)d_in[1];
  const float* wq_w     = (const float*)d_in[2];
  const float* wq_b     = (const float*)d_in[3];
  const float* wk_w     = (const float*)d_in[4];
  const float* wk_b     = (const float*)d_in[5];
  const float* wv_w     = (const float*)d_in[6];
  const float* wv_b     = (const float*)d_in[7];
  const float* wo_w     = (const float*)d_in[8];
  const float* wo_b     = (const float*)d_in[9];
  const float* wg_w     = (const float*)d_in[10];
  const float* wg_b     = (const float*)d_in[11];
  const float* qk_scale = (const float*)d_in[12];
  const float* kv_scale = (const float*)d_in[13];

  float* ws = (float*)d_ws;
  const size_t NT = (size_t)LS * DM;  // 786432
  float* q     = ws;
  float* k     = ws + NT;
  float* v     = ws + 2 * NT;
  float* sim   = ws + 3 * NT;
  float* gates = sim + NH * LS;
  float* m_s   = gates + NH * LS;
  float* Sraw  = m_s + NH * LS;
  float* g_s   = Sraw + NH * LS;
  float* states = g_s + NH * LS;                       // 12*64*4096 f32
  float* nes    = states + (size_t)NH * NTL * 4096;    // 12*64*64 f32
  u16*   xtb    = (u16*)(nes + (size_t)NH * NTL * HD); // NT bf16
  u16*   wT     = xtb + NT;                            // 4 * WSZ bf16
  u16*   lerpb  = wT + 4 * (size_t)WSZ;                // NT bf16
  u16*   pbase  = lerpb + NT;                          // 8 * NT bf16 partials

  conv_txw_kernel<<<dim3(2112), 256, 28672, stream>>>(
      x, filters, wq_w, wk_w, wv_w, wo_w, wT, pbase);
  pack_xt<<<dim3(NT / 2048), 256, 0, stream>>>(pbase, xtb);
  qkv_mfma<<<dim3(192), 256, 0, stream>>>(xtb, wT, wq_b, wk_b, wv_b, q, k, v);
  nsg_state_kernel<<<dim3(NTL, NH), 256, 0, stream>>>(
      q, k, v, wg_w, wg_b, qk_scale, kv_scale, sim, gates, states, nes);
  scan_prefix_kernel<<<dim3(NH, 4), 1024, 0, stream>>>(
      sim, gates, m_s, Sraw, g_s, states, nes);
  apply_kernel<<<dim3(NTL, NH), 256, 0, stream>>>(
      q, k, v, sim, gates, m_s, Sraw, g_s, states, nes, kv_scale, lerpb);
  out_mfma<<<dim3(192), 256, 0, stream>>>(
      lerpb, wT + 3 * (size_t)WSZ, wo_b, (float*)d_out);
}